// Round 6
// baseline (362.859 us; speedup 1.0000x reference)
//
#include <hip/hip_runtime.h>
#include <stdint.h>

typedef unsigned short u16;
typedef __attribute__((ext_vector_type(8))) short bf16x8;
typedef __attribute__((ext_vector_type(4))) float f32x4;
typedef __attribute__((ext_vector_type(4))) unsigned int u32x4;

__device__ __forceinline__ u16 f2b(float f) {
  uint32_t u = __float_as_uint(f);
  u += 0x7fffu + ((u >> 16) & 1u);
  return (u16)(u >> 16);
}
__device__ __forceinline__ float b2f(u16 h) {
  return __uint_as_float(((uint32_t)h) << 16);
}
// pack two f32 -> two bf16 (RTNE); HW packed cvt when available
__device__ __forceinline__ uint32_t pack2bf(float a, float b) {
#if __has_builtin(__builtin_amdgcn_cvt_pk_bf16_f32)
  typedef __attribute__((ext_vector_type(2))) __bf16 bf16x2_t;
  bf16x2_t r = __builtin_amdgcn_cvt_pk_bf16_f32(a, b);
  return __builtin_bit_cast(uint32_t, r);
#else
  return (uint32_t)f2b(a) | ((uint32_t)f2b(b) << 16);
#endif
}
// raw v_sqrt_f32 (skip libm denorm/inf fixup; feeds exp then bf16 round)
__device__ __forceinline__ float fast_sqrtf(float x) {
#if __has_builtin(__builtin_amdgcn_sqrtf)
  return __builtin_amdgcn_sqrtf(x);
#else
  return sqrtf(x);
#endif
}

__device__ __forceinline__ void gload_lds16(const u16* g, u16* l) {
  __builtin_amdgcn_global_load_lds(
      (const __attribute__((address_space(1))) void*)g,
      (__attribute__((address_space(3))) void*)l, 16, 0, 0);
}

// ---------------- GEMM: D[m,n] = sum_k A[m,k] * Bt[n,k] ------------------
// A: [M,K] bf16 row-major (lda), Bt: [N,K] bf16 row-major (ldb).
// 128x128 tile, BK=64, 4 waves, 4x4 MFMA 16x16x32, two k-steps per staging
// iter. (256^2 8-phase tried r1/r2: regressed at K=512, nt=8 — all
// fill/drain. BSUM2 reg-staged B tried r5: regressed — reg-staging
// serializes HBM latency that the gload_lds DMA path keeps async. This
// high-occupancy 2-blocks/CU DMA structure wins for short K; keep it.)
// A-ROW REMAP: MFMA block mi's logical row j loaded from physical tile
// row (j>>2)*8+(j&3)+{0,4,32,36}[mi] -> lane qd holds 8 contiguous output
// rows per col -> 16-B transposed stores.
// LDS SWIZZLE: row stride = 128 B = one full bank wrap, so banks depend
// only on the chunk. phys_chunk = logical ^ key(row) with key(row) =
// (row&3) | (((row>>3)&1)<<2): conflict-free (verified 0 bank conflicts).
// Block mapping: linear id -> batch = lin&7 (XCD colocation), then block
// coords. BYFAST=true puts the m-block (by) fastest after batch: use when
// the B operand is the large reused matrix (q/k-proj) -> L2 B-tile reuse
// (r4: proj FETCH 57->46 MB).
// Split-K: K = per-part len, C += part*pStride.
enum { EPI_BF16_T = 0, EPI_BF16_T_SQ = 1, EPI_F32_T = 2, EPI_RELU_BF16_T = 3,
       EPI_EXP_T = 4 };

template <int EPI, bool BYFAST = false>
__device__ __forceinline__ void gemm_body(
    u16* smem, const u16* A, size_t sA, int lda,
    const u16* B, size_t sB, int ldb,
    void* C, size_t sC, int ldc, int K, size_t pStride,
    const float* e_col2, const float* e_row2, float* e_l,
    int lin, int gx, int gy) {
  u16* As = smem;          // [128][64] u16
  u16* Bs = smem + 8192;   // [128][64] u16
  const int t = threadIdx.x;
  const int batch = lin & 7;
  const int rest = lin >> 3;
  int bx, by, part;
  if (BYFAST) {
    by = rest % gy;
    const int rx = rest / gy;
    bx = rx % gx;
    part = rx / gx;
  } else {
    bx = rest % gx;
    const int ry = rest / gx;
    by = ry % gy;
    part = ry / gy;
  }
  const int m0 = by * 128, n0 = bx * 128;
  const int koff = part * K;
  const u16* Ab = A + (size_t)batch * sA + (size_t)m0 * lda + koff;
  const u16* Bb = B + (size_t)batch * sB + (size_t)n0 * ldb + koff;
  // staging: thread t stages slots {t+256j}: row = slot>>3 = t>>3 + 32j,
  // phys chunk = t&7. key(row) is j-invariant. logical col = ((t&7)^key)*8.
  const int srow = t >> 3;
  const int skey = (srow & 3) | (((srow >> 3) & 1) << 2);
  const int scol = ((t & 7) ^ skey) << 3;
  const u16* aS = Ab + (size_t)srow * lda + scol;
  const u16* bS = Bb + (size_t)srow * ldb + scol;
  const size_t a32 = (size_t)32 * lda, b32 = (size_t)32 * ldb;
  u16* asDst = As + t * 8;
  u16* bsDst = Bs + t * 8;

  const int w = t >> 6, lane = t & 63;
  const int wm = (w >> 1) << 6, wn = (w & 1) << 6;
  const int qd = lane >> 4, l16 = lane & 15;
  const int rbase = ((l16 >> 2) << 3) + (l16 & 3);
  const int keyA = (l16 & 3) | (((l16 >> 2) & 1) << 2);
  const int keyB = (l16 & 3) | (((l16 >> 3) & 1) << 2);
  const u16* aRow0 = As + (wm + rbase) * 64;
  const u16* bRow0 = Bs + (wn + l16) * 64;

  f32x4 acc[4][4];
#pragma unroll
  for (int i = 0; i < 4; i++)
#pragma unroll
    for (int j = 0; j < 4; j++) acc[i][j] = (f32x4)0.0f;

  for (int k0 = 0; k0 < K; k0 += 64) {
    gload_lds16(aS, asDst);
    gload_lds16(aS + a32, asDst + 2048);
    gload_lds16(aS + 2 * a32, asDst + 4096);
    gload_lds16(aS + 3 * a32, asDst + 6144);
    gload_lds16(bS, bsDst);
    gload_lds16(bS + b32, bsDst + 2048);
    gload_lds16(bS + 2 * b32, bsDst + 4096);
    gload_lds16(bS + 3 * b32, bsDst + 6144);
    aS += 64;
    bS += 64;
    __syncthreads();  // drains vmcnt before barrier
#pragma unroll
    for (int s = 0; s < 2; s++) {
      const int ca = (((qd | (s << 2)) ^ keyA) << 3);
      const int cb = (((qd | (s << 2)) ^ keyB) << 3);
      bf16x8 af[4], bfr[4];
      af[0] = *(const bf16x8*)(aRow0 + ca);
      af[1] = *(const bf16x8*)(aRow0 + 4 * 64 + ca);
      af[2] = *(const bf16x8*)(aRow0 + 32 * 64 + ca);
      af[3] = *(const bf16x8*)(aRow0 + 36 * 64 + ca);
#pragma unroll
      for (int i = 0; i < 4; i++)
        bfr[i] = *(const bf16x8*)(bRow0 + i * 16 * 64 + cb);
#pragma unroll
      for (int mi = 0; mi < 4; mi++)
#pragma unroll
        for (int ni = 0; ni < 4; ni++)
          acc[mi][ni] = __builtin_amdgcn_mfma_f32_16x16x32_bf16(
              af[mi], bfr[ni], acc[mi][ni], 0, 0, 0);
    }
    __syncthreads();
  }

  // acc[2p+h][ni][r] holds phys row m0+wm+p*32+qd*8+h*4+r, col
  // n0+wn+ni*16+l16. Transposed stores: 8 contiguous rows per (p,ni).
  const size_t cbase = (size_t)part * pStride + (size_t)batch * sC;
  const int ncols = (int)(sC / ldc);

  if constexpr (EPI == EPI_EXP_T) {
    const int nrows = (int)(sA / lda);
    const float* col2 = e_col2 + (size_t)batch * ncols;  // q2 by col (l)
    const float* row2 = e_row2 + (size_t)batch * nrows;  // k2 by row (s)
    float* lb = e_l + (size_t)batch * ncols;
    float c2v[4];
#pragma unroll
    for (int ni = 0; ni < 4; ni++) c2v[ni] = col2[n0 + wn + ni * 16 + l16];
    float cs[4] = {0.f, 0.f, 0.f, 0.f};
#pragma unroll
    for (int p = 0; p < 2; p++) {
      const int prow = m0 + wm + p * 32 + qd * 8;
      float r2v[8];
#pragma unroll
      for (int r8 = 0; r8 < 8; r8++) r2v[r8] = row2[prow + r8];
#pragma unroll
      for (int ni = 0; ni < 4; ni++) {
        const int col = n0 + wn + ni * 16 + l16;
        float pv[8];
#pragma unroll
        for (int r = 0; r < 4; r++) {
          pv[r] = __expf(fast_sqrtf(
              fmaxf(c2v[ni] + r2v[r] - 2.0f * acc[2 * p][ni][r], 0.0f)));
          pv[4 + r] = __expf(fast_sqrtf(
              fmaxf(c2v[ni] + r2v[4 + r] - 2.0f * acc[2 * p + 1][ni][r], 0.0f)));
        }
#pragma unroll
        for (int j = 0; j < 8; j++) cs[ni] += pv[j];
        u32x4 wv;
        wv[0] = pack2bf(pv[0], pv[1]);
        wv[1] = pack2bf(pv[2], pv[3]);
        wv[2] = pack2bf(pv[4], pv[5]);
        wv[3] = pack2bf(pv[6], pv[7]);
        *(u32x4*)((u16*)C + cbase + (size_t)col * ldc + prow) = wv;
      }
    }
#pragma unroll
    for (int ni = 0; ni < 4; ni++) {
      cs[ni] += __shfl_xor(cs[ni], 16);
      cs[ni] += __shfl_xor(cs[ni], 32);
    }
    if (qd == 0) {
#pragma unroll
      for (int ni = 0; ni < 4; ni++)
        atomicAdd(lb + n0 + wn + ni * 16 + l16, cs[ni]);
    }
  } else if constexpr (EPI == EPI_F32_T) {
#pragma unroll
    for (int p = 0; p < 2; p++) {
      const int prow = m0 + wm + p * 32 + qd * 8;
#pragma unroll
      for (int ni = 0; ni < 4; ni++) {
        const int col = n0 + wn + ni * 16 + l16;
        float* dst = (float*)C + cbase + (size_t)col * ldc + prow;
        *(f32x4*)dst = acc[2 * p][ni];
        *(f32x4*)(dst + 4) = acc[2 * p + 1][ni];
      }
    }
  } else {
    // EPI_BF16_T / EPI_BF16_T_SQ / EPI_RELU_BF16_T
    float cs[4] = {0.f, 0.f, 0.f, 0.f};
#pragma unroll
    for (int p = 0; p < 2; p++) {
      const int prow = m0 + wm + p * 32 + qd * 8;
#pragma unroll
      for (int ni = 0; ni < 4; ni++) {
        const int col = n0 + wn + ni * 16 + l16;
        float v[8];
#pragma unroll
        for (int r = 0; r < 4; r++) {
          v[r] = acc[2 * p][ni][r];
          v[4 + r] = acc[2 * p + 1][ni][r];
        }
        if (EPI == EPI_RELU_BF16_T) {
#pragma unroll
          for (int j = 0; j < 8; j++) v[j] = fmaxf(v[j], 0.0f);
        }
        if (EPI == EPI_BF16_T_SQ) {
#pragma unroll
          for (int j = 0; j < 8; j++) cs[ni] += v[j] * v[j];
        }
        u32x4 wv;
        wv[0] = pack2bf(v[0], v[1]);
        wv[1] = pack2bf(v[2], v[3]);
        wv[2] = pack2bf(v[4], v[5]);
        wv[3] = pack2bf(v[6], v[7]);
        *(u32x4*)((u16*)C + cbase + (size_t)col * ldc + prow) = wv;
      }
    }
    if (EPI == EPI_BF16_T_SQ) {
#pragma unroll
      for (int ni = 0; ni < 4; ni++) {
        cs[ni] += __shfl_xor(cs[ni], 16);
        cs[ni] += __shfl_xor(cs[ni], 32);
      }
      if (qd == 0) {
#pragma unroll
        for (int ni = 0; ni < 4; ni++)
          atomicAdd(e_l + (size_t)batch * ncols + n0 + wn + ni * 16 + l16,
                    cs[ni]);
      }
    }
  }
}

template <int EPI>
__global__ __launch_bounds__(256, 2) void gemm_nt(
    const u16* __restrict__ A, size_t sA, int lda,
    const u16* __restrict__ B, size_t sB, int ldb,
    void* __restrict__ C, size_t sC, int ldc, int K, size_t pStride,
    const float* __restrict__ e_col2, const float* __restrict__ e_row2,
    float* __restrict__ e_l) {
  __shared__ __align__(16) u16 smem[16384];
  const int lin = blockIdx.x + gridDim.x * (blockIdx.y + gridDim.y * blockIdx.z);
  gemm_body<EPI>(smem, A, sA, lda, B, sB, ldb, C, sC, ldc, K, pStride,
                 e_col2, e_row2, e_l, lin, gridDim.x, gridDim.y);
}

// no-batch single-matrix gemm (r6): lin = blockIdx.x*8 -> batch 0.
// Used for WvmT = (Wv@Wm)^T: D[j,c] = sum_p WvN[j,p]*WmT[c,p] = Wvm[j,c];
// T-store -> array[c][j] = WvmT. 16 blocks, 0.27 GF, ~5 us.
template <int EPI>
__global__ __launch_bounds__(256, 2) void gemm_nt_nb(
    const u16* __restrict__ A, int lda, const u16* __restrict__ B, int ldb,
    void* __restrict__ C, size_t sC, int ldc, int K, int gx, int gy) {
  __shared__ __align__(16) u16 smem[16384];
  gemm_body<EPI>(smem, A, 0, lda, B, 0, ldb, C, sC, ldc, K, 0,
                 nullptr, nullptr, nullptr, (int)(blockIdx.x << 3), gx, gy);
}

// q/k/v projections in ONE launch (fewer launch gaps; tails overlap).
// q/k use BYFAST (B = h/sb is the big reused operand -> L2 B-tile reuse);
// v keeps bx-fastest (A = sb is the big operand, reused across bx).
// r6: v-proj consumes WvmT = (Wv@Wm)^T so vT holds v' = source@(Wv@Wm);
// attn.v then directly yields the Wm-projected message (associativity:
// (P@V/l)@Wm = (1/l)*P@(source@Wvm), exact) — the Wm gemm is GONE.
__global__ __launch_bounds__(256, 2) void proj_fused(
    const u16* __restrict__ WqT, const u16* __restrict__ WkT,
    const u16* __restrict__ WvmT, const u16* __restrict__ h,
    const u16* __restrict__ sb, u16* __restrict__ q, u16* __restrict__ kb,
    u16* __restrict__ vT, float* __restrict__ q2, float* __restrict__ k2) {
  __shared__ __align__(16) u16 smem[16384];
  const int lin = blockIdx.x;
  if (lin < 256) {
    // q-proj: result[d,l] -> T-store q[l,d]; col-sumsq -> q2[l]
    gemm_body<EPI_BF16_T_SQ, true>(smem, WqT, 0, 512, h, (size_t)1024 * 1024,
                                   1024, q, (size_t)1024 * 512, 512, 512, 0,
                                   nullptr, nullptr, q2, lin, 8, 4);
  } else if (lin < 1280) {
    // k-proj: result[d,s] -> T-store kb[s,d]; col-sumsq -> k2[s]
    gemm_body<EPI_BF16_T_SQ, true>(smem, WkT, 0, 512, sb, (size_t)4096 * 512,
                                   512, kb, (size_t)4096 * 512, 512, 512, 0,
                                   nullptr, nullptr, k2, lin - 256, 32, 4);
  } else {
    // v'-proj: result[s,c] -> T-store vT[c,s]
    gemm_body<EPI_BF16_T>(smem, sb, (size_t)4096 * 512, 512, WvmT, 0, 512,
                          vT, (size_t)512 * 4096, 4096, 512, 0, nullptr,
                          nullptr, nullptr, lin - 1280, 4, 32);
  }
}

// ---------------- prep_all: casts+zeroing AND weight transposes ----------
// blocks [0,20528): cast x->h, source->sb, zero q2/k2/lsum (256 thr each).
// blocks [20528,23088): 32x32 tiles. Wq/Wk/Wm transposed; Wv cast WITHOUT
// transpose (WvN, row-major bf16 — feeds the Wvm gemm as A); W1/W2
// transposed.
__global__ __launch_bounds__(256) void prep_all(
    const float* __restrict__ x, const float* __restrict__ sc,
    u16* __restrict__ h, u16* __restrict__ sb, float* __restrict__ q2,
    float* __restrict__ k2, float* __restrict__ lsum,
    const float* __restrict__ Wq, const float* __restrict__ Wk,
    const float* __restrict__ Wv, const float* __restrict__ Wm,
    const float* __restrict__ W1, const float* __restrict__ W2,
    u16* __restrict__ WqT, u16* __restrict__ WkT, u16* __restrict__ WvN,
    u16* __restrict__ WmT, u16* __restrict__ W1T, u16* __restrict__ W2T) {
  __shared__ float tile[32][33];
  const int blk = blockIdx.x;
  if (blk < 20528) {
    const size_t i = (size_t)blk * 256 + threadIdx.x;
    if (i < 1048576) {  // x: [N*L,512] -> h[:, 0:512] (row stride 1024)
      const float4 f = ((const float4*)x)[i];
      const int e = (int)(i << 2);
      const int row = e >> 9, col = e & 511;
      *(ushort4*)(h + ((size_t)row << 10) + col) =
          make_ushort4(f2b(f.x), f2b(f.y), f2b(f.z), f2b(f.w));
    } else if (i < 5242880) {
      const size_t j = i - 1048576;
      const float4 f = ((const float4*)sc)[j];
      *(ushort4*)(sb + (j << 2)) =
          make_ushort4(f2b(f.x), f2b(f.y), f2b(f.z), f2b(f.w));
    } else {
      const size_t j = i - 5242880;
      const float4 z = {0.f, 0.f, 0.f, 0.f};
      if (j < 2048) ((float4*)q2)[j] = z;
      else if (j < 10240) ((float4*)k2)[j - 2048] = z;
      else ((float4*)lsum)[j - 10240] = z;
    }
    return;
  }
  // transpose path: tb in [0,2560) = q,k,v,m (256 each) | W1 1024 | W2 512
  const int tb = blk - 20528;
  const float* W;
  u16* WT;
  int R, Cn, ldT, c0, r0, notr = 0;
  if (tb < 1024) {
    const int z = tb >> 8, local = tb & 255;
    switch (z) {
      case 0: W = Wq; WT = WqT; break;
      case 1: W = Wk; WT = WkT; break;
      case 2: W = Wv; WT = WvN; notr = 1; break;
      default: W = Wm; WT = WmT; break;
    }
    R = 512; Cn = 512; ldT = 512;
    c0 = (local & 15) << 5; r0 = (local >> 4) << 5;
  } else if (tb < 2048) {
    const int local = tb - 1024;
    W = W1; WT = W1T; R = 1024; Cn = 1024; ldT = 1024;
    c0 = (local & 31) << 5; r0 = (local >> 5) << 5;
  } else {
    const int local = tb - 2048;
    W = W2; WT = W2T; R = 1024; Cn = 512; ldT = 1024;
    c0 = (local & 15) << 5; r0 = (local >> 4) << 5;
  }
  const int tx = threadIdx.x & 31, ty = threadIdx.x >> 5;  // (32,8)
  for (int i = ty; i < 32; i += 8)
    tile[i][tx] = W[(size_t)(r0 + i) * Cn + c0 + tx];
  __syncthreads();
  if (notr) {
    for (int i = ty; i < 32; i += 8)
      WT[(size_t)(r0 + i) * Cn + c0 + tx] = f2b(tile[i][tx]);
  } else {
    for (int i = ty; i < 32; i += 8)
      WT[(size_t)(c0 + i) * ldT + r0 + tx] = f2b(tile[tx][i]);
  }
}

// h[row][512..1023] = bf16(LN((p0+p1)/lsum[row]; g,b)) over the 2 split-K
// f32 attn.v partials (already Wm-projected, r6). 1/lsum applied HERE
// (commutes exactly past Wm: per-row scale). 128 thr/row, float4 each.
__global__ __launch_bounds__(128) void ln_to_h(const float* __restrict__ mm,
                                               const float* __restrict__ lsum,
                                               const float* __restrict__ g,
                                               const float* __restrict__ b,
                                               u16* __restrict__ h) {
  const size_t row = blockIdx.x;
  const int t = threadIdx.x;
  const float inv = 1.0f / lsum[row];
  const float4 fa = ((const float4*)(mm + row * 512))[t];
  const float4 fb = ((const float4*)(mm + 4194304 + row * 512))[t];
  float4 f;
  f.x = (fa.x + fb.x) * inv; f.y = (fa.y + fb.y) * inv;
  f.z = (fa.z + fb.z) * inv; f.w = (fa.w + fb.w) * inv;
  float s = f.x + f.y + f.z + f.w;
  float sq = f.x * f.x + f.y * f.y + f.z * f.z + f.w * f.w;
#pragma unroll
  for (int off = 32; off; off >>= 1) { s += __shfl_xor(s, off); sq += __shfl_xor(sq, off); }
  __shared__ float rs_[2], rq_[2];
  if ((t & 63) == 0) { rs_[t >> 6] = s; rq_[t >> 6] = sq; }
  __syncthreads();
  s = rs_[0] + rs_[1]; sq = rq_[0] + rq_[1];
  const float mu = s * (1.0f / 512.0f);
  const float rstd = rsqrtf(sq * (1.0f / 512.0f) - mu * mu + 1e-5f);
  const float4 gv = ((const float4*)g)[t], bv = ((const float4*)b)[t];
  ushort4 o = make_ushort4(f2b((f.x - mu) * rstd * gv.x + bv.x),
                           f2b((f.y - mu) * rstd * gv.y + bv.y),
                           f2b((f.z - mu) * rstd * gv.z + bv.z),
                           f2b((f.w - mu) * rstd * gv.w + bv.w));
  *(ushort4*)(h + (row << 10) + 512 + (t << 2)) = o;
}

// out[row] = x[row] + LN(p0+p1; g,b) over 2 split-K f32 W2 partials.
__global__ __launch_bounds__(128) void ln_residual(const float* __restrict__ m2,
                                                   const float* __restrict__ x,
                                                   const float* __restrict__ g,
                                                   const float* __restrict__ b,
                                                   float* __restrict__ out) {
  const size_t row = blockIdx.x;
  const int t = threadIdx.x;
  const float4 fa = ((const float4*)(m2 + row * 512))[t];
  const float4 fb = ((const float4*)(m2 + 4194304 + row * 512))[t];
  float4 f;
  f.x = fa.x + fb.x; f.y = fa.y + fb.y; f.z = fa.z + fb.z; f.w = fa.w + fb.w;
  float s = f.x + f.y + f.z + f.w;
  float sq = f.x * f.x + f.y * f.y + f.z * f.z + f.w * f.w;
#pragma unroll
  for (int off = 32; off; off >>= 1) { s += __shfl_xor(s, off); sq += __shfl_xor(sq, off); }
  __shared__ float rs_[2], rq_[2];
  if ((t & 63) == 0) { rs_[t >> 6] = s; rq_[t >> 6] = sq; }
  __syncthreads();
  s = rs_[0] + rs_[1]; sq = rq_[0] + rq_[1];
  const float mu = s * (1.0f / 512.0f);
  const float rstd = rsqrtf(sq * (1.0f / 512.0f) - mu * mu + 1e-5f);
  const float4 gv = ((const float4*)g)[t], bv = ((const float4*)b)[t];
  const float4 xv = ((const float4*)(x + row * 512))[t];
  float4 o;
  o.x = xv.x + (f.x - mu) * rstd * gv.x + bv.x;
  o.y = xv.y + (f.y - mu) * rstd * gv.y + bv.y;
  o.z = xv.z + (f.z - mu) * rstd * gv.z + bv.z;
  o.w = xv.w + (f.w - mu) * rstd * gv.w + bv.w;
  ((float4*)(out + row * 512))[t] = o;
}

extern "C" void kernel_launch(void* const* d_in, const int* in_sizes, int n_in,
                              void* d_out, int out_size, void* d_ws, size_t ws_size,
                              hipStream_t stream) {
  const float* x  = (const float*)d_in[0];
  const float* sc = (const float*)d_in[1];
  const float* Wq = (const float*)d_in[2];
  const float* Wk = (const float*)d_in[3];
  const float* Wv = (const float*)d_in[4];
  const float* Wm = (const float*)d_in[5];
  const float* W1 = (const float*)d_in[6];
  const float* W2 = (const float*)d_in[7];
  const float* g1 = (const float*)d_in[8];
  const float* b1 = (const float*)d_in[9];
  const float* g2 = (const float*)d_in[10];
  const float* b2 = (const float*)d_in[11];
  float* out = (float*)d_out;
  char* ws = (char*)d_ws;

  constexpr int N = 8, L = 1024, S = 4096, D = 512;
  // workspace layout (bytes); peak = 231,899,136 (~221 MB)
  u16*   h    = (u16*)(ws + 0);          // [N*L,1024] bf16: x | ln1(message)
  u16*   sb   = (u16*)(ws + 16777216);   // [N*S,512] bf16 source
  u16*   WqT  = (u16*)(ws + 50331648);   // 512K
  u16*   WkT  = (u16*)(ws + 50855936);   // 512K
  u16*   WvN  = (u16*)(ws + 51380224);   // [512,512] bf16 Wv row-major
  u16*   WmT  = (u16*)(ws + 51904512);   // [512,512], 512K
  u16*   W1T  = (u16*)(ws + 52953088);   // [1024,1024], 2M
  u16*   W2T  = (u16*)(ws + 55050240);   // [512,1024], 1M
  u16*   q    = (u16*)(ws + 56098816);   // [N*L,512] (dead after qk gemm)
  u16*   kb   = (u16*)(ws + 64487424);   // [N*S,512] (dead after qk gemm)
  u16*   vT   = (u16*)(ws + 98041856);   // [N][512,S] v'=src@Wvm transposed
                                         // (dead after attn.v)
  float* lsum = (float*)(ws + 131596288);// [N*L] (dead after ln_to_h)
  float* q2   = (float*)(ws + 131629056);
  float* k2   = (float*)(ws + 131661824);
  u16*   qk   = (u16*)(ws + 164790272);  // [N*L,S] bf16 P=exp(dist), 64M
  u16*   WvmT = (u16*)(ws + 164790272);  // [512,512] (qk head — dead until
                                         // EXP gemm; consumed by proj)
  float* mm   = (float*)(ws + 64487424); // [2][N*L,512] f32 attn.v partials
                                         // (over kb, dead after EXP; ends
                                         //  exactly at vT)
  u16*   hh   = (u16*)(ws + 64487424);   // [N*L,1024] bf16 relu out (over
                                         // mm, dead after ln_to_h)
  float* m2   = (float*)(ws + 98041856); // [2][N*L,512] f32 W2 partials
                                         // (over vT, dead after attn.v)

  // phase 0: casts + zeroing + weight transposes (Wv cast non-transposed)
  prep_all<<<dim3(23088), 256, 0, stream>>>(x, sc, h, sb, q2, k2, lsum,
                                            Wq, Wk, Wv, Wm, W1, W2,
                                            WqT, WkT, WvN, WmT, W1T, W2T);

  // phase 0b: WvmT = (Wv@Wm)^T — tiny 16-block gemm (0.27 GF)
  gemm_nt_nb<EPI_BF16_T><<<dim3(16), 256, 0, stream>>>(
      WvN, 512, WmT, 512, WvmT, (size_t)512 * 512, 512, 512, 4, 4);

  // phase 1: q/k/v' projections in one launch
  proj_fused<<<dim3(2304), 256, 0, stream>>>(WqT, WkT, WvmT, h, sb, q, kb, vT,
                                             q2, k2);

  // phase 2: attention. EXP gemm: A=kb (rows s), Bt=q (cols l); T-store
  // lands P[l,s]; col sums -> lsum[l]. attn.v: A=v'T, Bt=P, split-K=2,
  // T-store f32 -> mm[l,c] partials (already Wm-projected; divide+LN in
  // ln_to_h).
  gemm_nt<EPI_EXP_T><<<dim3(8, 32, 8), 256, 0, stream>>>(
      kb, (size_t)S * 512, 512, q, (size_t)L * 512, 512, qk, (size_t)L * S, S,
      512, 0, q2, k2, lsum);
  gemm_nt<EPI_F32_T><<<dim3(8, 4, 16), 256, 0, stream>>>(
      vT, (size_t)D * S, S, qk, (size_t)L * S, S, mm, (size_t)L * 512, 512,
      2048, (size_t)(N * L) * 512, nullptr, nullptr, nullptr);

  // phase 3: LN1 (applies 1/lsum + partial sum) into h
  ln_to_h<<<dim3(N * L), 128, 0, stream>>>(mm, lsum, g1, b1, h);

  // phase 4: FFN (W2 split-K=2 -> 512 blocks, f32 partials)
  gemm_nt<EPI_RELU_BF16_T><<<dim3(8, 8, 8), 256, 0, stream>>>(
      W1T, 0, 1024, h, (size_t)L * 1024, 1024, hh, (size_t)L * 1024, 1024, 1024,
      0, nullptr, nullptr, nullptr);
  gemm_nt<EPI_F32_T><<<dim3(8, 4, 16), 256, 0, stream>>>(
      W2T, 0, 1024, hh, (size_t)L * 1024, 1024, m2, (size_t)L * 512, 512, 512,
      (size_t)(N * L) * 512, nullptr, nullptr, nullptr);

  // phase 5: LN2 + residual
  ln_residual<<<dim3(N * L), 128, 0, stream>>>(m2, x, g2, b2, out);
}

// Round 7
// 347.870 us; speedup vs baseline: 1.0431x; 1.0431x over previous
//
#include <hip/hip_runtime.h>
#include <stdint.h>

typedef unsigned short u16;
typedef __attribute__((ext_vector_type(8))) short bf16x8;
typedef __attribute__((ext_vector_type(4))) float f32x4;
typedef __attribute__((ext_vector_type(4))) unsigned int u32x4;

__device__ __forceinline__ u16 f2b(float f) {
  uint32_t u = __float_as_uint(f);
  u += 0x7fffu + ((u >> 16) & 1u);
  return (u16)(u >> 16);
}
__device__ __forceinline__ float b2f(u16 h) {
  return __uint_as_float(((uint32_t)h) << 16);
}
// pack two f32 -> two bf16 (RTNE); HW packed cvt when available
__device__ __forceinline__ uint32_t pack2bf(float a, float b) {
#if __has_builtin(__builtin_amdgcn_cvt_pk_bf16_f32)
  typedef __attribute__((ext_vector_type(2))) __bf16 bf16x2_t;
  bf16x2_t r = __builtin_amdgcn_cvt_pk_bf16_f32(a, b);
  return __builtin_bit_cast(uint32_t, r);
#else
  return (uint32_t)f2b(a) | ((uint32_t)f2b(b) << 16);
#endif
}
// raw v_sqrt_f32 (skip libm denorm/inf fixup; feeds exp then bf16 round)
__device__ __forceinline__ float fast_sqrtf(float x) {
#if __has_builtin(__builtin_amdgcn_sqrtf)
  return __builtin_amdgcn_sqrtf(x);
#else
  return sqrtf(x);
#endif
}

__device__ __forceinline__ void gload_lds16(const u16* g, u16* l) {
  __builtin_amdgcn_global_load_lds(
      (const __attribute__((address_space(1))) void*)g,
      (__attribute__((address_space(3))) void*)l, 16, 0, 0);
}

// ---------------- GEMM: D[m,n] = sum_k A[m,k] * Bt[n,k] ------------------
// A: [M,K] bf16 row-major (lda), Bt: [N,K] bf16 row-major (ldb).
// 128x128 tile, BK=64, 4 waves, 4x4 MFMA 16x16x32, two k-steps per staging
// iter. (256^2 8-phase tried r1/r2: regressed at K=512 — all fill/drain.
// BSUM2 reg-staged B tried r5: regressed — serializes HBM latency the
// gload_lds DMA keeps async.)
// r7 OCCUPANCY FIX: VGPR 60-68 + 64 AGPR acc (unified file) = 124-132 regs
// put every gemm in the 129-256 occupancy tier -> 8 waves/CU = 2 blocks/CU
// = the measured 25% OccupancyPercent. __launch_bounds__(256, 4) forces
// <=128 unified regs -> 16 waves/CU = 4 blocks/CU; K-loop live set is
// ~110-120 so no loop spills expected; epilogue spills (once/block) ok.
// 4 blocks/CU x 32KB LDS = 128KB <= 160KB.
// A-ROW REMAP: MFMA block mi's logical row j loaded from physical tile
// row (j>>2)*8+(j&3)+{0,4,32,36}[mi] -> lane qd holds 8 contiguous output
// rows per col -> 16-B transposed stores.
// LDS SWIZZLE: row stride = 128 B = one full bank wrap, so banks depend
// only on the chunk. phys_chunk = logical ^ key(row) with key(row) =
// (row&3) | (((row>>3)&1)<<2): conflict-free (verified 0 bank conflicts).
// Block mapping: linear id -> batch = lin&7 (XCD colocation), then block
// coords. BYFAST=true: m-block fastest after batch (B operand is the big
// reused matrix -> L2 B-tile reuse; r4: proj FETCH 57->46 MB).
// Split-K: K = per-part len, C += part*pStride.
enum { EPI_BF16_T = 0, EPI_BF16_T_SQ = 1, EPI_F32_T = 2, EPI_RELU_BF16_T = 3,
       EPI_EXP_T = 4 };

template <int EPI, bool BYFAST = false>
__device__ __forceinline__ void gemm_body(
    u16* smem, const u16* A, size_t sA, int lda,
    const u16* B, size_t sB, int ldb,
    void* C, size_t sC, int ldc, int K, size_t pStride,
    const float* e_col2, const float* e_row2, float* e_l,
    int lin, int gx, int gy) {
  u16* As = smem;          // [128][64] u16
  u16* Bs = smem + 8192;   // [128][64] u16
  const int t = threadIdx.x;
  const int batch = lin & 7;
  const int rest = lin >> 3;
  int bx, by, part;
  if (BYFAST) {
    by = rest % gy;
    const int rx = rest / gy;
    bx = rx % gx;
    part = rx / gx;
  } else {
    bx = rest % gx;
    const int ry = rest / gx;
    by = ry % gy;
    part = ry / gy;
  }
  const int m0 = by * 128, n0 = bx * 128;
  const int koff = part * K;
  const u16* Ab = A + (size_t)batch * sA + (size_t)m0 * lda + koff;
  const u16* Bb = B + (size_t)batch * sB + (size_t)n0 * ldb + koff;
  // staging: thread t stages slots {t+256j}: row = slot>>3 = t>>3 + 32j,
  // phys chunk = t&7. key(row) is j-invariant. logical col = ((t&7)^key)*8.
  const int srow = t >> 3;
  const int skey = (srow & 3) | (((srow >> 3) & 1) << 2);
  const int scol = ((t & 7) ^ skey) << 3;
  const u16* aS = Ab + (size_t)srow * lda + scol;
  const u16* bS = Bb + (size_t)srow * ldb + scol;
  const size_t a32 = (size_t)32 * lda, b32 = (size_t)32 * ldb;
  u16* asDst = As + t * 8;
  u16* bsDst = Bs + t * 8;

  const int w = t >> 6, lane = t & 63;
  const int wm = (w >> 1) << 6, wn = (w & 1) << 6;
  const int qd = lane >> 4, l16 = lane & 15;
  const int rbase = ((l16 >> 2) << 3) + (l16 & 3);
  const int keyA = (l16 & 3) | (((l16 >> 2) & 1) << 2);
  const int keyB = (l16 & 3) | (((l16 >> 3) & 1) << 2);
  const u16* aRow0 = As + (wm + rbase) * 64;
  const u16* bRow0 = Bs + (wn + l16) * 64;

  f32x4 acc[4][4];
#pragma unroll
  for (int i = 0; i < 4; i++)
#pragma unroll
    for (int j = 0; j < 4; j++) acc[i][j] = (f32x4)0.0f;

  for (int k0 = 0; k0 < K; k0 += 64) {
    gload_lds16(aS, asDst);
    gload_lds16(aS + a32, asDst + 2048);
    gload_lds16(aS + 2 * a32, asDst + 4096);
    gload_lds16(aS + 3 * a32, asDst + 6144);
    gload_lds16(bS, bsDst);
    gload_lds16(bS + b32, bsDst + 2048);
    gload_lds16(bS + 2 * b32, bsDst + 4096);
    gload_lds16(bS + 3 * b32, bsDst + 6144);
    aS += 64;
    bS += 64;
    __syncthreads();  // drains vmcnt before barrier
#pragma unroll
    for (int s = 0; s < 2; s++) {
      const int ca = (((qd | (s << 2)) ^ keyA) << 3);
      const int cb = (((qd | (s << 2)) ^ keyB) << 3);
      bf16x8 af[4], bfr[4];
      af[0] = *(const bf16x8*)(aRow0 + ca);
      af[1] = *(const bf16x8*)(aRow0 + 4 * 64 + ca);
      af[2] = *(const bf16x8*)(aRow0 + 32 * 64 + ca);
      af[3] = *(const bf16x8*)(aRow0 + 36 * 64 + ca);
#pragma unroll
      for (int i = 0; i < 4; i++)
        bfr[i] = *(const bf16x8*)(bRow0 + i * 16 * 64 + cb);
#pragma unroll
      for (int mi = 0; mi < 4; mi++)
#pragma unroll
        for (int ni = 0; ni < 4; ni++)
          acc[mi][ni] = __builtin_amdgcn_mfma_f32_16x16x32_bf16(
              af[mi], bfr[ni], acc[mi][ni], 0, 0, 0);
    }
    __syncthreads();
  }

  // acc[2p+h][ni][r] holds phys row m0+wm+p*32+qd*8+h*4+r, col
  // n0+wn+ni*16+l16. Transposed stores: 8 contiguous rows per (p,ni).
  const size_t cbase = (size_t)part * pStride + (size_t)batch * sC;
  const int ncols = (int)(sC / ldc);

  if constexpr (EPI == EPI_EXP_T) {
    const int nrows = (int)(sA / lda);
    const float* col2 = e_col2 + (size_t)batch * ncols;  // q2 by col (l)
    const float* row2 = e_row2 + (size_t)batch * nrows;  // k2 by row (s)
    float* lb = e_l + (size_t)batch * ncols;
    float c2v[4];
#pragma unroll
    for (int ni = 0; ni < 4; ni++) c2v[ni] = col2[n0 + wn + ni * 16 + l16];
    float cs[4] = {0.f, 0.f, 0.f, 0.f};
#pragma unroll
    for (int p = 0; p < 2; p++) {
      const int prow = m0 + wm + p * 32 + qd * 8;
      float r2v[8];
#pragma unroll
      for (int r8 = 0; r8 < 8; r8++) r2v[r8] = row2[prow + r8];
#pragma unroll
      for (int ni = 0; ni < 4; ni++) {
        const int col = n0 + wn + ni * 16 + l16;
        float pv[8];
#pragma unroll
        for (int r = 0; r < 4; r++) {
          pv[r] = __expf(fast_sqrtf(
              fmaxf(c2v[ni] + r2v[r] - 2.0f * acc[2 * p][ni][r], 0.0f)));
          pv[4 + r] = __expf(fast_sqrtf(
              fmaxf(c2v[ni] + r2v[4 + r] - 2.0f * acc[2 * p + 1][ni][r], 0.0f)));
        }
#pragma unroll
        for (int j = 0; j < 8; j++) cs[ni] += pv[j];
        u32x4 wv;
        wv[0] = pack2bf(pv[0], pv[1]);
        wv[1] = pack2bf(pv[2], pv[3]);
        wv[2] = pack2bf(pv[4], pv[5]);
        wv[3] = pack2bf(pv[6], pv[7]);
        *(u32x4*)((u16*)C + cbase + (size_t)col * ldc + prow) = wv;
      }
    }
#pragma unroll
    for (int ni = 0; ni < 4; ni++) {
      cs[ni] += __shfl_xor(cs[ni], 16);
      cs[ni] += __shfl_xor(cs[ni], 32);
    }
    if (qd == 0) {
#pragma unroll
      for (int ni = 0; ni < 4; ni++)
        atomicAdd(lb + n0 + wn + ni * 16 + l16, cs[ni]);
    }
  } else if constexpr (EPI == EPI_F32_T) {
#pragma unroll
    for (int p = 0; p < 2; p++) {
      const int prow = m0 + wm + p * 32 + qd * 8;
#pragma unroll
      for (int ni = 0; ni < 4; ni++) {
        const int col = n0 + wn + ni * 16 + l16;
        float* dst = (float*)C + cbase + (size_t)col * ldc + prow;
        *(f32x4*)dst = acc[2 * p][ni];
        *(f32x4*)(dst + 4) = acc[2 * p + 1][ni];
      }
    }
  } else {
    // EPI_BF16_T / EPI_BF16_T_SQ / EPI_RELU_BF16_T
    float cs[4] = {0.f, 0.f, 0.f, 0.f};
#pragma unroll
    for (int p = 0; p < 2; p++) {
      const int prow = m0 + wm + p * 32 + qd * 8;
#pragma unroll
      for (int ni = 0; ni < 4; ni++) {
        const int col = n0 + wn + ni * 16 + l16;
        float v[8];
#pragma unroll
        for (int r = 0; r < 4; r++) {
          v[r] = acc[2 * p][ni][r];
          v[4 + r] = acc[2 * p + 1][ni][r];
        }
        if (EPI == EPI_RELU_BF16_T) {
#pragma unroll
          for (int j = 0; j < 8; j++) v[j] = fmaxf(v[j], 0.0f);
        }
        if (EPI == EPI_BF16_T_SQ) {
#pragma unroll
          for (int j = 0; j < 8; j++) cs[ni] += v[j] * v[j];
        }
        u32x4 wv;
        wv[0] = pack2bf(v[0], v[1]);
        wv[1] = pack2bf(v[2], v[3]);
        wv[2] = pack2bf(v[4], v[5]);
        wv[3] = pack2bf(v[6], v[7]);
        *(u32x4*)((u16*)C + cbase + (size_t)col * ldc + prow) = wv;
      }
    }
    if (EPI == EPI_BF16_T_SQ) {
#pragma unroll
      for (int ni = 0; ni < 4; ni++) {
        cs[ni] += __shfl_xor(cs[ni], 16);
        cs[ni] += __shfl_xor(cs[ni], 32);
      }
      if (qd == 0) {
#pragma unroll
        for (int ni = 0; ni < 4; ni++)
          atomicAdd(e_l + (size_t)batch * ncols + n0 + wn + ni * 16 + l16,
                    cs[ni]);
      }
    }
  }
}

template <int EPI>
__global__ __launch_bounds__(256, 4) void gemm_nt(
    const u16* __restrict__ A, size_t sA, int lda,
    const u16* __restrict__ B, size_t sB, int ldb,
    void* __restrict__ C, size_t sC, int ldc, int K, size_t pStride,
    const float* __restrict__ e_col2, const float* __restrict__ e_row2,
    float* __restrict__ e_l) {
  __shared__ __align__(16) u16 smem[16384];
  const int lin = blockIdx.x + gridDim.x * (blockIdx.y + gridDim.y * blockIdx.z);
  gemm_body<EPI>(smem, A, sA, lda, B, sB, ldb, C, sC, ldc, K, pStride,
                 e_col2, e_row2, e_l, lin, gridDim.x, gridDim.y);
}

// no-batch single-matrix gemm: lin = blockIdx.x*8 -> batch 0.
// Used for WvmT = (Wv@Wm)^T: D[j,c] = sum_p WvN[j,p]*WmT[c,p] = Wvm[j,c];
// T-store -> array[c][j] = WvmT. 16 blocks, 0.27 GF.
template <int EPI>
__global__ __launch_bounds__(256, 4) void gemm_nt_nb(
    const u16* __restrict__ A, int lda, const u16* __restrict__ B, int ldb,
    void* __restrict__ C, size_t sC, int ldc, int K, int gx, int gy) {
  __shared__ __align__(16) u16 smem[16384];
  gemm_body<EPI>(smem, A, 0, lda, B, 0, ldb, C, sC, ldc, K, 0,
                 nullptr, nullptr, nullptr, (int)(blockIdx.x << 3), gx, gy);
}

// q/k/v projections in ONE launch (fewer launch gaps; tails overlap).
// q/k use BYFAST (B = h/sb is the big reused operand -> L2 B-tile reuse);
// v keeps bx-fastest (A = sb is the big operand, reused across bx).
// r6: v-proj consumes WvmT = (Wv@Wm)^T so vT holds v' = source@(Wv@Wm);
// attn.v then directly yields the Wm-projected message (associativity:
// (P@V/l)@Wm = (1/l)*P@(source@Wvm), exact) — no separate Wm gemm.
__global__ __launch_bounds__(256, 4) void proj_fused(
    const u16* __restrict__ WqT, const u16* __restrict__ WkT,
    const u16* __restrict__ WvmT, const u16* __restrict__ h,
    const u16* __restrict__ sb, u16* __restrict__ q, u16* __restrict__ kb,
    u16* __restrict__ vT, float* __restrict__ q2, float* __restrict__ k2) {
  __shared__ __align__(16) u16 smem[16384];
  const int lin = blockIdx.x;
  if (lin < 256) {
    // q-proj: result[d,l] -> T-store q[l,d]; col-sumsq -> q2[l]
    gemm_body<EPI_BF16_T_SQ, true>(smem, WqT, 0, 512, h, (size_t)1024 * 1024,
                                   1024, q, (size_t)1024 * 512, 512, 512, 0,
                                   nullptr, nullptr, q2, lin, 8, 4);
  } else if (lin < 1280) {
    // k-proj: result[d,s] -> T-store kb[s,d]; col-sumsq -> k2[s]
    gemm_body<EPI_BF16_T_SQ, true>(smem, WkT, 0, 512, sb, (size_t)4096 * 512,
                                   512, kb, (size_t)4096 * 512, 512, 512, 0,
                                   nullptr, nullptr, k2, lin - 256, 32, 4);
  } else {
    // v'-proj: result[s,c] -> T-store vT[c,s]
    gemm_body<EPI_BF16_T>(smem, sb, (size_t)4096 * 512, 512, WvmT, 0, 512,
                          vT, (size_t)512 * 4096, 4096, 512, 0, nullptr,
                          nullptr, nullptr, lin - 1280, 4, 32);
  }
}

// ---------------- prep_all: casts+zeroing AND weight transposes ----------
// blocks [0,20528): cast x->h, source->sb, zero q2/k2/lsum (256 thr each).
// blocks [20528,23088): 32x32 tiles. Wq/Wk/Wm transposed; Wv cast WITHOUT
// transpose (WvN, row-major bf16 — feeds the Wvm gemm as A); W1/W2
// transposed.
__global__ __launch_bounds__(256) void prep_all(
    const float* __restrict__ x, const float* __restrict__ sc,
    u16* __restrict__ h, u16* __restrict__ sb, float* __restrict__ q2,
    float* __restrict__ k2, float* __restrict__ lsum,
    const float* __restrict__ Wq, const float* __restrict__ Wk,
    const float* __restrict__ Wv, const float* __restrict__ Wm,
    const float* __restrict__ W1, const float* __restrict__ W2,
    u16* __restrict__ WqT, u16* __restrict__ WkT, u16* __restrict__ WvN,
    u16* __restrict__ WmT, u16* __restrict__ W1T, u16* __restrict__ W2T) {
  __shared__ float tile[32][33];
  const int blk = blockIdx.x;
  if (blk < 20528) {
    const size_t i = (size_t)blk * 256 + threadIdx.x;
    if (i < 1048576) {  // x: [N*L,512] -> h[:, 0:512] (row stride 1024)
      const float4 f = ((const float4*)x)[i];
      const int e = (int)(i << 2);
      const int row = e >> 9, col = e & 511;
      *(ushort4*)(h + ((size_t)row << 10) + col) =
          make_ushort4(f2b(f.x), f2b(f.y), f2b(f.z), f2b(f.w));
    } else if (i < 5242880) {
      const size_t j = i - 1048576;
      const float4 f = ((const float4*)sc)[j];
      *(ushort4*)(sb + (j << 2)) =
          make_ushort4(f2b(f.x), f2b(f.y), f2b(f.z), f2b(f.w));
    } else {
      const size_t j = i - 5242880;
      const float4 z = {0.f, 0.f, 0.f, 0.f};
      if (j < 2048) ((float4*)q2)[j] = z;
      else if (j < 10240) ((float4*)k2)[j - 2048] = z;
      else ((float4*)lsum)[j - 10240] = z;
    }
    return;
  }
  // transpose path: tb in [0,2560) = q,k,v,m (256 each) | W1 1024 | W2 512
  const int tb = blk - 20528;
  const float* W;
  u16* WT;
  int R, Cn, ldT, c0, r0, notr = 0;
  if (tb < 1024) {
    const int z = tb >> 8, local = tb & 255;
    switch (z) {
      case 0: W = Wq; WT = WqT; break;
      case 1: W = Wk; WT = WkT; break;
      case 2: W = Wv; WT = WvN; notr = 1; break;
      default: W = Wm; WT = WmT; break;
    }
    R = 512; Cn = 512; ldT = 512;
    c0 = (local & 15) << 5; r0 = (local >> 4) << 5;
  } else if (tb < 2048) {
    const int local = tb - 1024;
    W = W1; WT = W1T; R = 1024; Cn = 1024; ldT = 1024;
    c0 = (local & 31) << 5; r0 = (local >> 5) << 5;
  } else {
    const int local = tb - 2048;
    W = W2; WT = W2T; R = 1024; Cn = 512; ldT = 1024;
    c0 = (local & 15) << 5; r0 = (local >> 4) << 5;
  }
  const int tx = threadIdx.x & 31, ty = threadIdx.x >> 5;  // (32,8)
  for (int i = ty; i < 32; i += 8)
    tile[i][tx] = W[(size_t)(r0 + i) * Cn + c0 + tx];
  __syncthreads();
  if (notr) {
    for (int i = ty; i < 32; i += 8)
      WT[(size_t)(r0 + i) * Cn + c0 + tx] = f2b(tile[i][tx]);
  } else {
    for (int i = ty; i < 32; i += 8)
      WT[(size_t)(c0 + i) * ldT + r0 + tx] = f2b(tile[tx][i]);
  }
}

// h[row][512..1023] = bf16(LN((p0+p1)/lsum[row]; g,b)) over the 2 split-K
// f32 attn.v partials (already Wm-projected). 1/lsum applied HERE
// (commutes exactly past Wm: per-row scale). 128 thr/row, float4 each.
__global__ __launch_bounds__(128) void ln_to_h(const float* __restrict__ mm,
                                               const float* __restrict__ lsum,
                                               const float* __restrict__ g,
                                               const float* __restrict__ b,
                                               u16* __restrict__ h) {
  const size_t row = blockIdx.x;
  const int t = threadIdx.x;
  const float inv = 1.0f / lsum[row];
  const float4 fa = ((const float4*)(mm + row * 512))[t];
  const float4 fb = ((const float4*)(mm + 4194304 + row * 512))[t];
  float4 f;
  f.x = (fa.x + fb.x) * inv; f.y = (fa.y + fb.y) * inv;
  f.z = (fa.z + fb.z) * inv; f.w = (fa.w + fb.w) * inv;
  float s = f.x + f.y + f.z + f.w;
  float sq = f.x * f.x + f.y * f.y + f.z * f.z + f.w * f.w;
#pragma unroll
  for (int off = 32; off; off >>= 1) { s += __shfl_xor(s, off); sq += __shfl_xor(sq, off); }
  __shared__ float rs_[2], rq_[2];
  if ((t & 63) == 0) { rs_[t >> 6] = s; rq_[t >> 6] = sq; }
  __syncthreads();
  s = rs_[0] + rs_[1]; sq = rq_[0] + rq_[1];
  const float mu = s * (1.0f / 512.0f);
  const float rstd = rsqrtf(sq * (1.0f / 512.0f) - mu * mu + 1e-5f);
  const float4 gv = ((const float4*)g)[t], bv = ((const float4*)b)[t];
  ushort4 o = make_ushort4(f2b((f.x - mu) * rstd * gv.x + bv.x),
                           f2b((f.y - mu) * rstd * gv.y + bv.y),
                           f2b((f.z - mu) * rstd * gv.z + bv.z),
                           f2b((f.w - mu) * rstd * gv.w + bv.w));
  *(ushort4*)(h + (row << 10) + 512 + (t << 2)) = o;
}

// out[row] = x[row] + LN(p0+p1; g,b) over 2 split-K f32 W2 partials.
__global__ __launch_bounds__(128) void ln_residual(const float* __restrict__ m2,
                                                   const float* __restrict__ x,
                                                   const float* __restrict__ g,
                                                   const float* __restrict__ b,
                                                   float* __restrict__ out) {
  const size_t row = blockIdx.x;
  const int t = threadIdx.x;
  const float4 fa = ((const float4*)(m2 + row * 512))[t];
  const float4 fb = ((const float4*)(m2 + 4194304 + row * 512))[t];
  float4 f;
  f.x = fa.x + fb.x; f.y = fa.y + fb.y; f.z = fa.z + fb.z; f.w = fa.w + fb.w;
  float s = f.x + f.y + f.z + f.w;
  float sq = f.x * f.x + f.y * f.y + f.z * f.z + f.w * f.w;
#pragma unroll
  for (int off = 32; off; off >>= 1) { s += __shfl_xor(s, off); sq += __shfl_xor(sq, off); }
  __shared__ float rs_[2], rq_[2];
  if ((t & 63) == 0) { rs_[t >> 6] = s; rq_[t >> 6] = sq; }
  __syncthreads();
  s = rs_[0] + rs_[1]; sq = rq_[0] + rq_[1];
  const float mu = s * (1.0f / 512.0f);
  const float rstd = rsqrtf(sq * (1.0f / 512.0f) - mu * mu + 1e-5f);
  const float4 gv = ((const float4*)g)[t], bv = ((const float4*)b)[t];
  const float4 xv = ((const float4*)(x + row * 512))[t];
  float4 o;
  o.x = xv.x + (f.x - mu) * rstd * gv.x + bv.x;
  o.y = xv.y + (f.y - mu) * rstd * gv.y + bv.y;
  o.z = xv.z + (f.z - mu) * rstd * gv.z + bv.z;
  o.w = xv.w + (f.w - mu) * rstd * gv.w + bv.w;
  ((float4*)(out + row * 512))[t] = o;
}

extern "C" void kernel_launch(void* const* d_in, const int* in_sizes, int n_in,
                              void* d_out, int out_size, void* d_ws, size_t ws_size,
                              hipStream_t stream) {
  const float* x  = (const float*)d_in[0];
  const float* sc = (const float*)d_in[1];
  const float* Wq = (const float*)d_in[2];
  const float* Wk = (const float*)d_in[3];
  const float* Wv = (const float*)d_in[4];
  const float* Wm = (const float*)d_in[5];
  const float* W1 = (const float*)d_in[6];
  const float* W2 = (const float*)d_in[7];
  const float* g1 = (const float*)d_in[8];
  const float* b1 = (const float*)d_in[9];
  const float* g2 = (const float*)d_in[10];
  const float* b2 = (const float*)d_in[11];
  float* out = (float*)d_out;
  char* ws = (char*)d_ws;

  constexpr int N = 8, L = 1024, S = 4096, D = 512;
  // workspace layout (bytes); peak = 231,899,136 (~221 MB)
  u16*   h    = (u16*)(ws + 0);          // [N*L,1024] bf16: x | ln1(message)
  u16*   sb   = (u16*)(ws + 16777216);   // [N*S,512] bf16 source
  u16*   WqT  = (u16*)(ws + 50331648);   // 512K
  u16*   WkT  = (u16*)(ws + 50855936);   // 512K
  u16*   WvN  = (u16*)(ws + 51380224);   // [512,512] bf16 Wv row-major
  u16*   WmT  = (u16*)(ws + 51904512);   // [512,512], 512K
  u16*   W1T  = (u16*)(ws + 52953088);   // [1024,1024], 2M
  u16*   W2T  = (u16*)(ws + 55050240);   // [512,1024], 1M
  u16*   q    = (u16*)(ws + 56098816);   // [N*L,512] (dead after qk gemm)
  u16*   kb   = (u16*)(ws + 64487424);   // [N*S,512] (dead after qk gemm)
  u16*   vT   = (u16*)(ws + 98041856);   // [N][512,S] v'=src@Wvm transposed
                                         // (dead after attn.v)
  float* lsum = (float*)(ws + 131596288);// [N*L] (dead after ln_to_h)
  float* q2   = (float*)(ws + 131629056);
  float* k2   = (float*)(ws + 131661824);
  u16*   qk   = (u16*)(ws + 164790272);  // [N*L,S] bf16 P=exp(dist), 64M
  u16*   WvmT = (u16*)(ws + 164790272);  // [512,512] (qk head — dead until
                                         // EXP gemm; consumed by proj)
  float* mm   = (float*)(ws + 64487424); // [2][N*L,512] f32 attn.v partials
                                         // (over kb, dead after EXP; ends
                                         //  exactly at vT)
  u16*   hh   = (u16*)(ws + 64487424);   // [N*L,1024] bf16 relu out (over
                                         // mm, dead after ln_to_h)
  float* m2   = (float*)(ws + 98041856); // [2][N*L,512] f32 W2 partials
                                         // (over vT, dead after attn.v)

  // phase 0: casts + zeroing + weight transposes (Wv cast non-transposed)
  prep_all<<<dim3(23088), 256, 0, stream>>>(x, sc, h, sb, q2, k2, lsum,
                                            Wq, Wk, Wv, Wm, W1, W2,
                                            WqT, WkT, WvN, WmT, W1T, W2T);

  // phase 0b: WvmT = (Wv@Wm)^T — tiny 16-block gemm (0.27 GF)
  gemm_nt_nb<EPI_BF16_T><<<dim3(16), 256, 0, stream>>>(
      WvN, 512, WmT, 512, WvmT, (size_t)512 * 512, 512, 512, 4, 4);

  // phase 1: q/k/v' projections in one launch
  proj_fused<<<dim3(2304), 256, 0, stream>>>(WqT, WkT, WvmT, h, sb, q, kb, vT,
                                             q2, k2);

  // phase 2: attention. EXP gemm: A=kb (rows s), Bt=q (cols l); T-store
  // lands P[l,s]; col sums -> lsum[l]. attn.v: A=v'T, Bt=P, split-K=2,
  // T-store f32 -> mm[l,c] partials (already Wm-projected; divide+LN in
  // ln_to_h).
  gemm_nt<EPI_EXP_T><<<dim3(8, 32, 8), 256, 0, stream>>>(
      kb, (size_t)S * 512, 512, q, (size_t)L * 512, 512, qk, (size_t)L * S, S,
      512, 0, q2, k2, lsum);
  gemm_nt<EPI_F32_T><<<dim3(8, 4, 16), 256, 0, stream>>>(
      vT, (size_t)D * S, S, qk, (size_t)L * S, S, mm, (size_t)L * 512, 512,
      2048, (size_t)(N * L) * 512, nullptr, nullptr, nullptr);

  // phase 3: LN1 (applies 1/lsum + partial sum) into h
  ln_to_h<<<dim3(N * L), 128, 0, stream>>>(mm, lsum, g1, b1, h);

  // phase 4: FFN (W2 split-K=2 -> 512 blocks, f32 partials)
  gemm_nt<EPI_RELU_BF16_T><<<dim3(8, 8, 8), 256, 0, stream>>>(
      W1T, 0, 1024, h, (size_t)L * 1024, 1024, hh, (size_t)L * 1024, 1024, 1024,
      0, nullptr, nullptr, nullptr);
  gemm_nt<EPI_F32_T><<<dim3(8, 4, 16), 256, 0, stream>>>(
      W2T, 0, 1024, hh, (size_t)L * 1024, 1024, m2, (size_t)L * 512, 512, 512,
      (size_t)(N * L) * 512, nullptr, nullptr, nullptr);

  // phase 5: LN2 + residual
  ln_residual<<<dim3(N * L), 128, 0, stream>>>(m2, x, g2, b2, out);
}